// Round 13
// baseline (134.091 us; speedup 1.0000x reference)
//
#include <hip/hip_runtime.h>
#include <hip/hip_fp16.h>

#define NS 256
#define N2 (NS * NS)          // 65536
#define HID 32
#define T_STEPS 64

typedef _Float16 h2     __attribute__((ext_vector_type(2)));
typedef _Float16 half8  __attribute__((ext_vector_type(8)));
typedef float    float4v __attribute__((ext_vector_type(4)));

union H8 { half8 v8; h2 v2[4]; };

// cvt_pkrtz returns __fp16x2; bit-identical to our h2 (_Float16x2)
__device__ __forceinline__ h2 pk(float a, float b) {
    return __builtin_bit_cast(h2, __builtin_amdgcn_cvt_pkrtz(a, b));
}

// packed-f16 ELU: max(z, exp2(min(z,0)*log2e) - 1)
__device__ __forceinline__ h2 elu2(h2 z) {
    h2 zero; zero[0] = (_Float16)0.f; zero[1] = (_Float16)0.f;
    h2 zm  = __builtin_elementwise_min(z, zero);
    h2 e   = __builtin_elementwise_exp2(zm * (_Float16)1.442695041f);
    h2 em1 = e + (_Float16)(-1.0f);
    return __builtin_elementwise_max(z, em1);
}

__global__ __launch_bounds__(256, 6) void mlpconv_lds_kernel(
    const float* __restrict__ x,
    const float* __restrict__ W0, const float* __restrict__ b0,
    const float* __restrict__ W1, const float* __restrict__ b1,
    const float* __restrict__ W2, const float* __restrict__ b2,
    float* __restrict__ out)
{
    // 6 rows: block's 4 output rows + up/down halo. Rows are contiguous global
    // rows (mod 256), so flat LDS indexing reproduces numpy flat-wrap for the
    // l channel automatically (incl. row-0 / j=0 cases).
    __shared__ float lds[6 * NS];

    const int tid  = threadIdx.x;
    const int lane = tid & 63;
    const int m    = lane & 15;   // point col (B col / C-D col / A row)
    const int kg   = lane >> 4;   // k-group: this lane's A/B k-slots are 8kg..8kg+7

    // Channel permutation so each MFMA's D lands directly in the next MFMA's
    // B-frag layout (validated rounds 7-11).
    const int c0 = 8 * (m >> 2) + (m & 3);
    const int c1 = c0 + 4;

    // ---- persistent MFMA fragments ----
    H8 a00, a01;          // layer-0 A = W0^T permuted, k>=5 rows zero
    #pragma unroll
    for (int i = 0; i < 8; ++i) {
        const int k = 8 * kg + i;
        a00.v8[i] = (k < 5) ? (_Float16)W0[k * HID + c0] : (_Float16)0.f;
        a01.v8[i] = (k < 5) ? (_Float16)W0[k * HID + c1] : (_Float16)0.f;
    }
    H8 a10, a11;          // layer-1 A = W1^T permuted
    #pragma unroll
    for (int i = 0; i < 8; ++i) {
        a10.v8[i] = (_Float16)W1[(8 * kg + i) * HID + c0];
        a11.v8[i] = (_Float16)W1[(8 * kg + i) * HID + c1];
    }
    H8 a2;                // layer-2 A: row 0 = W2, other rows zero
    #pragma unroll
    for (int i = 0; i < 8; ++i)
        a2.v8[i] = (m == 0) ? (_Float16)W2[8 * kg + i] : (_Float16)0.f;

    float4v cl0a, cl0b, cl1a, cl1b;   // biases pre-placed in C/D layout
    #pragma unroll
    for (int r = 0; r < 4; ++r) {
        cl0a[r] = b0[8 * kg + r];
        cl0b[r] = b0[8 * kg + 4 + r];
        cl1a[r] = b1[8 * kg + r];
        cl1b[r] = b1[8 * kg + 4 + r];
    }
    float4v c2;
    c2[0] = (kg == 0) ? b2[0] : 0.0f;
    c2[1] = 0.0f; c2[2] = 0.0f; c2[3] = 0.0f;

    asm volatile("" : "+v"(a00.v8), "+v"(a01.v8), "+v"(a10.v8), "+v"(a11.v8),
                      "+v"(a2.v8), "+v"(cl0a), "+v"(cl0b), "+v"(cl1a), "+v"(cl1b));

    // ---- stage 6 rows into LDS (coalesced, one-time) ----
    const int t    = blockIdx.y;
    const int i0b  = blockIdx.x * 4;             // block's first output row
    const float* __restrict__ xt = x   + ((size_t)t << 16);
    float* __restrict__       ob = out + ((size_t)t << 16);

    #pragma unroll
    for (int it = 0; it < 6; ++it) {
        const int gr = (i0b + 255 + it) & 255;   // rows i0b-1 .. i0b+4 (mod 256)
        lds[it * NS + tid] = xt[(gr << 8) | tid];
    }
    __syncthreads();

    // ---- wave -> one grid row; stencil reads = ds_read with imm offsets ----
    const int wid = __builtin_amdgcn_readfirstlane(tid >> 6);
    const int i0  = i0b + wid;
    const int sbase = i0 << 8;

    // vaddr points at this wave's UP row, col m (byte address).
    // reads per tile l (all compile-time immediates):
    //   l2 : +64l        c : +1024+64l     l : +1020+64l   (global-flat contiguity)
    //   r  : +1028+64l   r2: +2048+64l
    const float* vp = &lds[wid * NS + m];
    // r-channel fix for (m==15, tile 15): row-periodic -> center row col 0.
    const float* vpR = (m == 15) ? &lds[(wid + 1) * NS] : (vp + 256 + 1 + 240);

    float res[16];

    #pragma unroll
    for (int l = 0; l < 16; ++l) {
        const int o = 16 * l;
        const float s0 = vp[256 + o - 1];                 // l
        const float s1 = vp[o];                           // l2
        const float s2 = vp[256 + o];                     // c
        const float s3 = (l == 15) ? *vpR : vp[256 + o + 1];  // r (row-periodic)
        const float s4 = vp[512 + o];                     // r2

        // B-frag for layer 0: k-slots 0..4 = inputs; rest finite filler.
        H8 bf;
        bf.v2[0] = pk(s0, s1);
        bf.v2[1] = pk(s2, s3);
        bf.v2[2] = pk(s4, s4);
        bf.v2[3] = bf.v2[2];

        // layer 0
        float4v d0 = __builtin_amdgcn_mfma_f32_16x16x32_f16(a00.v8, bf.v8, cl0a, 0, 0, 0);
        float4v d1 = __builtin_amdgcn_mfma_f32_16x16x32_f16(a01.v8, bf.v8, cl0b, 0, 0, 0);

        H8 hf;
        hf.v2[0] = elu2(pk(d0[0], d0[1]));
        hf.v2[1] = elu2(pk(d0[2], d0[3]));
        hf.v2[2] = elu2(pk(d1[0], d1[1]));
        hf.v2[3] = elu2(pk(d1[2], d1[3]));

        // layer 1
        float4v e0 = __builtin_amdgcn_mfma_f32_16x16x32_f16(a10.v8, hf.v8, cl1a, 0, 0, 0);
        float4v e1 = __builtin_amdgcn_mfma_f32_16x16x32_f16(a11.v8, hf.v8, cl1b, 0, 0, 0);

        H8 gf;
        gf.v2[0] = elu2(pk(e0[0], e0[1]));
        gf.v2[1] = elu2(pk(e0[2], e0[3]));
        gf.v2[2] = elu2(pk(e1[0], e1[1]));
        gf.v2[3] = elu2(pk(e1[2], e1[3]));

        // layer 2: D row 0 (kg==0, r==0) = b2 + sum_k W2[k]*gf[k]
        float4v dz = __builtin_amdgcn_mfma_f32_16x16x32_f16(a2.v8, gf.v8, c2, 0, 0, 0);

        res[l] = dz[0];
    }

    // One divergent region: kg==0 lanes hold all results for their column.
    if (kg == 0) {
        const unsigned vc0 = (unsigned)(sbase + m);
        #pragma unroll
        for (int l = 0; l < 16; ++l)
            ob[vc0 + 16u * (unsigned)l] = res[l];
    }
}

extern "C" void kernel_launch(void* const* d_in, const int* in_sizes, int n_in,
                              void* d_out, int out_size, void* d_ws, size_t ws_size,
                              hipStream_t stream) {
    const float* x  = (const float*)d_in[0];
    const float* W0 = (const float*)d_in[1];
    const float* b0 = (const float*)d_in[2];
    const float* W1 = (const float*)d_in[3];
    const float* b1 = (const float*)d_in[4];
    const float* W2 = (const float*)d_in[5];
    const float* b2 = (const float*)d_in[6];
    float* out = (float*)d_out;

    dim3 grid(NS / 4, T_STEPS);   // 64 x 64 blocks; block = 4 waves = 4 rows
    mlpconv_lds_kernel<<<grid, dim3(256), 0, stream>>>(
        x, W0, b0, W1, b1, W2, b2, out);
}

// Round 14
// 133.592 us; speedup vs baseline: 1.0037x; 1.0037x over previous
//
#include <hip/hip_runtime.h>
#include <hip/hip_fp16.h>

#define NS 256
#define N2 (NS * NS)          // 65536
#define HID 32
#define T_STEPS 64

typedef _Float16 h2     __attribute__((ext_vector_type(2)));
typedef _Float16 half8  __attribute__((ext_vector_type(8)));
typedef float    float4v __attribute__((ext_vector_type(4)));

union H8 { half8 v8; h2 v2[4]; };

// cvt_pkrtz returns __fp16x2; bit-identical to our h2 (_Float16x2)
__device__ __forceinline__ h2 pk(float a, float b) {
    return __builtin_bit_cast(h2, __builtin_amdgcn_cvt_pkrtz(a, b));
}

// scalar f32 ELU on MFMA outputs: 5 plain VALU instrs, no pack/unpack.
// max(z, exp(min(z,0))-1): z>0 -> max(z, 0)=z ; z<=0 -> exp(z)-1
__device__ __forceinline__ float eluf(float z) {
    return fmaxf(z, __expf(fminf(z, 0.0f)) - 1.0f);
}

__global__ __launch_bounds__(256, 4) void mlpconv_ldsf32_kernel(
    const float* __restrict__ x,
    const float* __restrict__ W0, const float* __restrict__ b0,
    const float* __restrict__ W1, const float* __restrict__ b1,
    const float* __restrict__ W2, const float* __restrict__ b2,
    float* __restrict__ out)
{
    // 6 rows: block's 4 output rows + up/down halo (validated round 13).
    __shared__ float lds[6 * NS];

    const int tid  = threadIdx.x;
    const int lane = tid & 63;
    const int m    = lane & 15;   // point col (B col / C-D col / A row)
    const int kg   = lane >> 4;   // k-group: this lane's A/B k-slots are 8kg..8kg+7

    // Channel permutation so each MFMA's D lands directly in the next MFMA's
    // B-frag layout (validated rounds 7-13).
    const int c0 = 8 * (m >> 2) + (m & 3);
    const int c1 = c0 + 4;

    // ---- persistent MFMA fragments ----
    H8 a00, a01;          // layer-0 A = W0^T permuted, k>=5 rows zero
    #pragma unroll
    for (int i = 0; i < 8; ++i) {
        const int k = 8 * kg + i;
        a00.v8[i] = (k < 5) ? (_Float16)W0[k * HID + c0] : (_Float16)0.f;
        a01.v8[i] = (k < 5) ? (_Float16)W0[k * HID + c1] : (_Float16)0.f;
    }
    H8 a10, a11;          // layer-1 A = W1^T permuted
    #pragma unroll
    for (int i = 0; i < 8; ++i) {
        a10.v8[i] = (_Float16)W1[(8 * kg + i) * HID + c0];
        a11.v8[i] = (_Float16)W1[(8 * kg + i) * HID + c1];
    }
    H8 a2;                // layer-2 A: row 0 = W2, other rows zero
    #pragma unroll
    for (int i = 0; i < 8; ++i)
        a2.v8[i] = (m == 0) ? (_Float16)W2[8 * kg + i] : (_Float16)0.f;

    float4v cl0a, cl0b, cl1a, cl1b;   // biases pre-placed in C/D layout
    #pragma unroll
    for (int r = 0; r < 4; ++r) {
        cl0a[r] = b0[8 * kg + r];
        cl0b[r] = b0[8 * kg + 4 + r];
        cl1a[r] = b1[8 * kg + r];
        cl1b[r] = b1[8 * kg + 4 + r];
    }
    float4v c2;
    c2[0] = (kg == 0) ? b2[0] : 0.0f;
    c2[1] = 0.0f; c2[2] = 0.0f; c2[3] = 0.0f;

    asm volatile("" : "+v"(a00.v8), "+v"(a01.v8), "+v"(a10.v8), "+v"(a11.v8),
                      "+v"(a2.v8), "+v"(cl0a), "+v"(cl0b), "+v"(cl1a), "+v"(cl1b));

    // ---- stage 6 rows into LDS (coalesced, one-time) ----
    const int t    = blockIdx.y;
    const int i0b  = blockIdx.x * 4;             // block's first output row
    const float* __restrict__ xt = x   + ((size_t)t << 16);
    float* __restrict__       ob = out + ((size_t)t << 16);

    #pragma unroll
    for (int it = 0; it < 6; ++it) {
        const int gr = (i0b + 255 + it) & 255;   // rows i0b-1 .. i0b+4 (mod 256)
        lds[it * NS + tid] = xt[(gr << 8) | tid];
    }
    __syncthreads();

    // ---- wave -> one grid row; stencil reads = ds_read with imm offsets ----
    const int wid = __builtin_amdgcn_readfirstlane(tid >> 6);
    const int i0  = i0b + wid;
    const int sbase = i0 << 8;

    const float* vp = &lds[wid * NS + m];
    // r-channel fix for (m==15, tile 15): row-periodic -> center row col 0.
    const float* vpR = (m == 15) ? &lds[(wid + 1) * NS] : (vp + 256 + 1 + 240);

    float res[16];

    #pragma unroll
    for (int l = 0; l < 16; ++l) {
        const int o = 16 * l;
        const float s0 = vp[256 + o - 1];                 // l
        const float s1 = vp[o];                           // l2
        const float s2 = vp[256 + o];                     // c
        const float s3 = (l == 15) ? *vpR : vp[256 + o + 1];  // r (row-periodic)
        const float s4 = vp[512 + o];                     // r2

        // B-frag for layer 0: k-slots 0..4 = inputs; rest finite filler.
        H8 bf;
        bf.v2[0] = pk(s0, s1);
        bf.v2[1] = pk(s2, s3);
        bf.v2[2] = pk(s4, s4);
        bf.v2[3] = bf.v2[2];

        // layer 0
        float4v d0 = __builtin_amdgcn_mfma_f32_16x16x32_f16(a00.v8, bf.v8, cl0a, 0, 0, 0);
        float4v d1 = __builtin_amdgcn_mfma_f32_16x16x32_f16(a01.v8, bf.v8, cl0b, 0, 0, 0);

        // ELU in scalar f32 (on f32 MFMA outputs), pack once per pair.
        H8 hf;
        hf.v2[0] = pk(eluf(d0[0]), eluf(d0[1]));
        hf.v2[1] = pk(eluf(d0[2]), eluf(d0[3]));
        hf.v2[2] = pk(eluf(d1[0]), eluf(d1[1]));
        hf.v2[3] = pk(eluf(d1[2]), eluf(d1[3]));

        // layer 1
        float4v e0 = __builtin_amdgcn_mfma_f32_16x16x32_f16(a10.v8, hf.v8, cl1a, 0, 0, 0);
        float4v e1 = __builtin_amdgcn_mfma_f32_16x16x32_f16(a11.v8, hf.v8, cl1b, 0, 0, 0);

        H8 gf;
        gf.v2[0] = pk(eluf(e0[0]), eluf(e0[1]));
        gf.v2[1] = pk(eluf(e0[2]), eluf(e0[3]));
        gf.v2[2] = pk(eluf(e1[0]), eluf(e1[1]));
        gf.v2[3] = pk(eluf(e1[2]), eluf(e1[3]));

        // layer 2: D row 0 (kg==0, r==0) = b2 + sum_k W2[k]*gf[k]
        float4v dz = __builtin_amdgcn_mfma_f32_16x16x32_f16(a2.v8, gf.v8, c2, 0, 0, 0);

        res[l] = dz[0];
    }

    // One divergent region: kg==0 lanes hold all results for their column.
    if (kg == 0) {
        const unsigned vc0 = (unsigned)(sbase + m);
        #pragma unroll
        for (int l = 0; l < 16; ++l)
            ob[vc0 + 16u * (unsigned)l] = res[l];
    }
}

extern "C" void kernel_launch(void* const* d_in, const int* in_sizes, int n_in,
                              void* d_out, int out_size, void* d_ws, size_t ws_size,
                              hipStream_t stream) {
    const float* x  = (const float*)d_in[0];
    const float* W0 = (const float*)d_in[1];
    const float* b0 = (const float*)d_in[2];
    const float* W1 = (const float*)d_in[3];
    const float* b1 = (const float*)d_in[4];
    const float* W2 = (const float*)d_in[5];
    const float* b2 = (const float*)d_in[6];
    float* out = (float*)d_out;

    dim3 grid(NS / 4, T_STEPS);   // 64 x 64 blocks; block = 4 waves = 4 rows
    mlpconv_ldsf32_kernel<<<grid, dim3(256), 0, stream>>>(
        x, W0, b0, W1, b1, W2, b2, out);
}

// Round 15
// 125.975 us; speedup vs baseline: 1.0644x; 1.0605x over previous
//
#include <hip/hip_runtime.h>
#include <hip/hip_fp16.h>

#define NS 256
#define N2 (NS * NS)          // 65536
#define HID 32
#define T_STEPS 64

typedef _Float16 h2     __attribute__((ext_vector_type(2)));
typedef _Float16 half8  __attribute__((ext_vector_type(8)));
typedef float    float4v __attribute__((ext_vector_type(4)));

union H8 { half8 v8; h2 v2[4]; };

// cvt_pkrtz returns __fp16x2; bit-identical to our h2 (_Float16x2)
__device__ __forceinline__ h2 pk(float a, float b) {
    return __builtin_bit_cast(h2, __builtin_amdgcn_cvt_pkrtz(a, b));
}

// packed-f16 ELU: max(z, exp2(min(z,0)*log2e) - 1)  [r13-measured cheapest]
__device__ __forceinline__ h2 elu2(h2 z) {
    h2 zero; zero[0] = (_Float16)0.f; zero[1] = (_Float16)0.f;
    h2 zm  = __builtin_elementwise_min(z, zero);
    h2 e   = __builtin_elementwise_exp2(zm * (_Float16)1.442695041f);
    h2 em1 = e + (_Float16)(-1.0f);
    return __builtin_elementwise_max(z, em1);
}

__global__ __launch_bounds__(256, 4) void mlpconv_r15_kernel(
    const float* __restrict__ x,
    const float* __restrict__ W0, const float* __restrict__ b0,
    const float* __restrict__ W1, const float* __restrict__ b1,
    const float* __restrict__ W2, const float* __restrict__ b2,
    float* __restrict__ out)
{
    // 6 rows: block's 4 output rows + up/down halo (validated round 13).
    __shared__ float lds[6 * NS];

    const int tid  = threadIdx.x;
    const int lane = tid & 63;
    const int m    = lane & 15;   // point col (B col / C-D col / A row)
    const int kg   = lane >> 4;   // k-group: this lane's A/B k-slots are 8kg..8kg+7

    // Channel permutation so each MFMA's D lands directly in the next MFMA's
    // B-frag layout (validated rounds 7-14).
    const int c0 = 8 * (m >> 2) + (m & 3);
    const int c1 = c0 + 4;

    // ---- persistent MFMA fragments (lean: 40 VGPRs pinned) ----
    H8 a00, a01;          // layer-0 A = W0^T permuted, k>=5 rows zero
    #pragma unroll
    for (int i = 0; i < 8; ++i) {
        const int k = 8 * kg + i;
        a00.v8[i] = (k < 5) ? (_Float16)W0[k * HID + c0] : (_Float16)0.f;
        a01.v8[i] = (k < 5) ? (_Float16)W0[k * HID + c1] : (_Float16)0.f;
    }
    H8 a10, a11;          // layer-1 A = W1^T permuted
    #pragma unroll
    for (int i = 0; i < 8; ++i) {
        a10.v8[i] = (_Float16)W1[(8 * kg + i) * HID + c0];
        a11.v8[i] = (_Float16)W1[(8 * kg + i) * HID + c1];
    }
    H8 a2;                // layer-2 A: row 0 = W2, other rows zero
    #pragma unroll
    for (int i = 0; i < 8; ++i)
        a2.v8[i] = (m == 0) ? (_Float16)W2[8 * kg + i] : (_Float16)0.f;

    float4v cl0a, cl0b, cl1a, cl1b;   // biases pre-placed in C/D layout
    #pragma unroll
    for (int r = 0; r < 4; ++r) {
        cl0a[r] = b0[8 * kg + r];
        cl0b[r] = b0[8 * kg + 4 + r];
        cl1a[r] = b1[8 * kg + r];
        cl1b[r] = b1[8 * kg + 4 + r];
    }
    float4v c2;
    c2[0] = (kg == 0) ? b2[0] : 0.0f;
    c2[1] = 0.0f; c2[2] = 0.0f; c2[3] = 0.0f;

    asm volatile("" : "+v"(a00.v8), "+v"(a01.v8), "+v"(a10.v8), "+v"(a11.v8),
                      "+v"(a2.v8), "+v"(cl0a), "+v"(cl0b), "+v"(cl1a), "+v"(cl1b));

    // ---- stage 6 rows into LDS (coalesced, one-time) ----
    const int t    = blockIdx.y;
    const int i0b  = blockIdx.x * 4;             // block's first output row
    const float* __restrict__ xt = x   + ((size_t)t << 16);
    float* __restrict__       ob = out + ((size_t)t << 16);

    #pragma unroll
    for (int it = 0; it < 6; ++it) {
        const int gr = (i0b + 255 + it) & 255;   // rows i0b-1 .. i0b+4 (mod 256)
        lds[it * NS + tid] = xt[(gr << 8) | tid];
    }
    __syncthreads();

    // ---- wave -> one grid row; stencil reads = ds_read with imm offsets ----
    const int wid = __builtin_amdgcn_readfirstlane(tid >> 6);
    const int i0  = i0b + wid;
    const unsigned vc0 = (unsigned)((i0 << 8) + m);

    const float* vp = &lds[wid * NS + m];
    // r-channel fix for (m==15, tile 15): row-periodic -> center row col 0.
    const float* vpR = (m == 15) ? &lds[(wid + 1) * NS] : (vp + 256 + 1 + 240);

    #pragma unroll
    for (int l = 0; l < 16; ++l) {
        const int o = 16 * l;
        const float s0 = vp[256 + o - 1];                 // l
        const float s1 = vp[o];                           // l2
        const float s2 = vp[256 + o];                     // c
        const float s3 = (l == 15) ? *vpR : vp[256 + o + 1];  // r (row-periodic)
        const float s4 = vp[512 + o];                     // r2

        // B-frag for layer 0: k-slots 0..4 = inputs; rest finite filler.
        H8 bf;
        bf.v2[0] = pk(s0, s1);
        bf.v2[1] = pk(s2, s3);
        bf.v2[2] = pk(s4, s4);
        bf.v2[3] = bf.v2[2];

        // layer 0
        float4v d0 = __builtin_amdgcn_mfma_f32_16x16x32_f16(a00.v8, bf.v8, cl0a, 0, 0, 0);
        float4v d1 = __builtin_amdgcn_mfma_f32_16x16x32_f16(a01.v8, bf.v8, cl0b, 0, 0, 0);

        H8 hf;
        hf.v2[0] = elu2(pk(d0[0], d0[1]));
        hf.v2[1] = elu2(pk(d0[2], d0[3]));
        hf.v2[2] = elu2(pk(d1[0], d1[1]));
        hf.v2[3] = elu2(pk(d1[2], d1[3]));

        // layer 1
        float4v e0 = __builtin_amdgcn_mfma_f32_16x16x32_f16(a10.v8, hf.v8, cl1a, 0, 0, 0);
        float4v e1 = __builtin_amdgcn_mfma_f32_16x16x32_f16(a11.v8, hf.v8, cl1b, 0, 0, 0);

        H8 gf;
        gf.v2[0] = elu2(pk(e0[0], e0[1]));
        gf.v2[1] = elu2(pk(e0[2], e0[3]));
        gf.v2[2] = elu2(pk(e1[0], e1[1]));
        gf.v2[3] = elu2(pk(e1[2], e1[3]));

        // layer 2: D row 0 (kg==0, r==0) = b2 + sum_k W2[k]*gf[k]
        float4v dz = __builtin_amdgcn_mfma_f32_16x16x32_f16(a2.v8, gf.v8, c2, 0, 0, 0);

        // per-tile masked store (r7-measured: cheap, register-lean)
        if (kg == 0) ob[vc0 + (unsigned)o] = dz[0];
    }
}

extern "C" void kernel_launch(void* const* d_in, const int* in_sizes, int n_in,
                              void* d_out, int out_size, void* d_ws, size_t ws_size,
                              hipStream_t stream) {
    const float* x  = (const float*)d_in[0];
    const float* W0 = (const float*)d_in[1];
    const float* b0 = (const float*)d_in[2];
    const float* W1 = (const float*)d_in[3];
    const float* b1 = (const float*)d_in[4];
    const float* W2 = (const float*)d_in[5];
    const float* b2 = (const float*)d_in[6];
    float* out = (float*)d_out;

    dim3 grid(NS / 4, T_STEPS);   // 64 x 64 blocks; block = 4 waves = 4 rows
    mlpconv_r15_kernel<<<grid, dim3(256), 0, stream>>>(
        x, W0, b0, W1, b1, W2, b2, out);
}